// Round 3
// baseline (135.251 us; speedup 1.0000x reference)
//
#include <hip/hip_runtime.h>
#include <math.h>

// TeacherMLP fused forward.
// R3 changes vs R2:
//  - Total parallelism is 2048 rows x 256 neurons = 524288 threads = 8192
//    waves = exactly 100% device occupancy at 1 (row,neuron)/thread.
//  - Tall blocks: 1024 threads = (4 rows x 256 neurons), 512 blocks
//    = 2 blocks/CU = 32 waves/CU. The 4 row-wave-groups share the weight
//    stream via L1 (in-block reuse x4), activations via LDS broadcast.
//  - Layer 2 (128 outs): split-K across 2 groups + LDS combine, all
//    1024 threads busy.
// R2 counters motivating this: VALUBusy 74%, Occupancy 30% -> latency-bound
// on mul->exp2->add->rcp->add chain with only 4 waves/SIMD.

__device__ __forceinline__ float fast_rcp(float x)  { return __builtin_amdgcn_rcpf(x); }
__device__ __forceinline__ float fast_exp2(float x) { return __builtin_amdgcn_exp2f(x); }

#define SC  2.885390081777927f      /* 2*log2(e): exp2(SC*z) = e^{2z} */
#define INV (1.0f / 2.885390081777927f)
#define INV2PI 0.15915494309189535f /* 1/(2pi) for v_sin (revolutions) */

__global__ void weff_kernel(const float* __restrict__ W0, const int* __restrict__ I0,
                            const float* __restrict__ W1, const int* __restrict__ I1,
                            const float* __restrict__ W2, const int* __restrict__ I2,
                            float* __restrict__ ws) {
    int tid = blockIdx.x * blockDim.x + threadIdx.x;   // 0 .. 163839
    const float* W; const int* I; float* out; int outd; int e;
    if (tid < 65536)        { W = W0; I = I0; out = ws;          outd = 256; e = tid; }
    else if (tid < 131072)  { W = W1; I = I1; out = ws + 65536;  outd = 256; e = tid - 65536; }
    else if (tid < 163840)  { W = W2; I = I2; out = ws + 131072; outd = 128; e = tid - 131072; }
    else return;
    int o = e >> 8;       // out index (in-dim is always 256)
    int i = e & 255;      // in index
    float w = W[e];       // coalesced (e = o*256 + i)
    int idx = I[e];
    // branchless atoms: [id, sin, tanh, square]
    float sn = __builtin_amdgcn_sinf(w * INV2PI);               // hw sin, revolutions
    float th = 1.0f - 2.0f * fast_rcp(fast_exp2(w * SC) + 1.0f);
    float sq = w * w;
    float v = (idx == 1) ? sn : (idx == 2) ? th : (idx == 3) ? sq : w;
    // packed store: [i/4][o][i%4] -> main loop reads float4 of 4 K-values
    out[(i >> 2) * (outd * 4) + o * 4 + (i & 3)] = v;
}

__global__ __launch_bounds__(1024, 8) void mlp_kernel(
    const float* __restrict__ x,  const float* __restrict__ b0,
    const float* __restrict__ b1, const float* __restrict__ b2,
    const float* __restrict__ ws, float* __restrict__ out) {
    // packed float4 views: index = (i>>2)*outd + o
    const float4* We0 = (const float4*)ws;             // [64][256]
    const float4* We1 = (const float4*)(ws + 65536);   // [64][256]
    const float4* We2 = (const float4*)(ws + 131072);  // [64][128]

    __shared__ __align__(16) float hA[4][256];
    __shared__ __align__(16) float hB[4][256];

    const int t = threadIdx.x;
    const int r = t >> 8;               // 0..3: row within block (wave-uniform)
    const int o = t & 255;              // output neuron for layers 0,1
    const int row0 = blockIdx.x * 4;

    // stage 4 input rows, pre-scaled by SC (coalesced, one elem/thread)
    hA[r][o] = x[(row0 + r) * 256 + o] * SC;
    __syncthreads();

    // ---------------- layer 0: hA -> hB (tanh) ----------------
    {
        const float bias = b0[o];
        float acc = 0.f;
#pragma unroll 4
        for (int ic = 0; ic < 64; ic++) {
            float4 w = We0[ic * 256 + o];                // L1-shared across 4 r-groups
            float4 h = *(const float4*)&hA[r][ic * 4];   // LDS same-addr broadcast
            acc += fast_rcp(fast_exp2(h.x * w.x) + 1.f);
            acc += fast_rcp(fast_exp2(h.y * w.y) + 1.f);
            acc += fast_rcp(fast_exp2(h.z * w.z) + 1.f);
            acc += fast_rcp(fast_exp2(h.w * w.w) + 1.f);
        }
        hB[r][o] = (256.0f - 2.0f * acc + bias) * SC;
        __syncthreads();
    }

    // ---------------- layer 1: hB -> hA (tanh) ----------------
    {
        const float bias = b1[o];
        float acc = 0.f;
#pragma unroll 4
        for (int ic = 0; ic < 64; ic++) {
            float4 w = We1[ic * 256 + o];
            float4 h = *(const float4*)&hB[r][ic * 4];
            acc += fast_rcp(fast_exp2(h.x * w.x) + 1.f);
            acc += fast_rcp(fast_exp2(h.y * w.y) + 1.f);
            acc += fast_rcp(fast_exp2(h.z * w.z) + 1.f);
            acc += fast_rcp(fast_exp2(h.w * w.w) + 1.f);
        }
        hA[r][o] = (256.0f - 2.0f * acc + bias) * SC;
        __syncthreads();
    }

    // ---------------- layer 2: hA -> out (identity matmul, split-K) -------
    {
        const int o2 = t & 127;          // output neuron
        const int kk = (t >> 7) & 1;     // K-half
        float acc = 0.f;
#pragma unroll 4
        for (int ic = kk * 32; ic < kk * 32 + 32; ic++) {
            float4 w = We2[ic * 128 + o2];
            float4 h = *(const float4*)&hA[r][ic * 4];
            acc += h.x * w.x + h.y * w.y + h.z * w.z + h.w * w.w;
        }
        // partials into hB (free after the post-layer-1 barrier): [r][kk*128+o2]
        hB[r][kk * 128 + o2] = acc;
        __syncthreads();
        if (t < 512) {
            int rr = t >> 7, oo = t & 127;
            out[(row0 + rr) * 128 + oo] =
                (hB[rr][oo] + hB[rr][128 + oo]) * INV + b2[oo];
        }
    }
}

extern "C" void kernel_launch(void* const* d_in, const int* in_sizes, int n_in,
                              void* d_out, int out_size, void* d_ws, size_t ws_size,
                              hipStream_t stream) {
    const float* x  = (const float*)d_in[0];
    const float* W0 = (const float*)d_in[1];
    const float* b0 = (const float*)d_in[2];
    const int*   I0 = (const int*)  d_in[3];
    const float* W1 = (const float*)d_in[4];
    const float* b1 = (const float*)d_in[5];
    const int*   I1 = (const int*)  d_in[6];
    const float* W2 = (const float*)d_in[7];
    const float* b2 = (const float*)d_in[8];
    const int*   I2 = (const int*)  d_in[9];
    float* ws  = (float*)d_ws;    // 163840 floats = 655360 B
    float* out = (float*)d_out;

    weff_kernel<<<640, 256, 0, stream>>>(W0, I0, W1, I1, W2, I2, ws);
    mlp_kernel<<<512, 1024, 0, stream>>>(x, b0, b1, b2, ws, out);
}

// Round 4
// 125.872 us; speedup vs baseline: 1.0745x; 1.0745x over previous
//
#include <hip/hip_runtime.h>
#include <math.h>

// TeacherMLP fused forward.
// R4 changes vs R2/R3:
//  - Back to R2 launch config (RB=2, 256-thr blocks, 1024 blocks): R3 proved
//    occupancy is NOT the lever (30%->64% occ made dur WORSE 66.9->73.6).
//    Model fit: trans ops (v_exp_f32/v_rcp_f32) execute at ~1/8 rate
//    (16 cyc/wave64) and dominate: 304 cyc/chunk predicts 65us ~= measured.
//  - Merge-4 sigmoid algebra: sum_{i=0..3} 1/Ai = (P2*S1 + P1*S2)/(P1*P2),
//    Ai = exp2(ti)+1 -> 5 trans per 4 elements (was 8). Requires t <= 30
//    clamp (inf would make inf/inf = NaN in the product form; den <= 2^120).
//  - Predicted: 304 -> 240 cyc/chunk -> mlp ~53us.

#define RB 2  // batch rows per block

__device__ __forceinline__ float fast_rcp(float x)  { return __builtin_amdgcn_rcpf(x); }
__device__ __forceinline__ float fast_exp2(float x) { return __builtin_amdgcn_exp2f(x); }

#define SC  2.885390081777927f      /* 2*log2(e): exp2(SC*z) = e^{2z} */
#define INV (1.0f / 2.885390081777927f)
#define INV2PI 0.15915494309189535f /* 1/(2pi) for v_sin (revolutions) */

__global__ void weff_kernel(const float* __restrict__ W0, const int* __restrict__ I0,
                            const float* __restrict__ W1, const int* __restrict__ I1,
                            const float* __restrict__ W2, const int* __restrict__ I2,
                            float* __restrict__ ws) {
    int tid = blockIdx.x * blockDim.x + threadIdx.x;   // 0 .. 163839
    const float* W; const int* I; float* out; int outd; int e;
    if (tid < 65536)        { W = W0; I = I0; out = ws;          outd = 256; e = tid; }
    else if (tid < 131072)  { W = W1; I = I1; out = ws + 65536;  outd = 256; e = tid - 65536; }
    else if (tid < 163840)  { W = W2; I = I2; out = ws + 131072; outd = 128; e = tid - 131072; }
    else return;
    int o = e >> 8;       // out index (in-dim is always 256)
    int i = e & 255;      // in index
    float w = W[e];       // coalesced (e = o*256 + i)
    int idx = I[e];
    // branchless atoms: [id, sin, tanh, square]
    float sn = __builtin_amdgcn_sinf(w * INV2PI);               // hw sin, revolutions
    float th = 1.0f - 2.0f * fast_rcp(fast_exp2(w * SC) + 1.0f);
    float sq = w * w;
    float v = (idx == 1) ? sn : (idx == 2) ? th : (idx == 3) ? sq : w;
    // packed store: [i/4][o][i%4] -> main loop reads float4 of 4 K-values
    out[(i >> 2) * (outd * 4) + o * 4 + (i & 3)] = v;
}

// sum of 4 sigmoid-terms 1/(exp2(t_k)+1) with ONE rcp.
// t_k must be clamped <= 30 so products stay finite (den <= 2^120).
__device__ __forceinline__ float sig4(float4 h, float4 w) {
    float t0 = fminf(h.x * w.x, 30.f);
    float t1 = fminf(h.y * w.y, 30.f);
    float t2 = fminf(h.z * w.z, 30.f);
    float t3 = fminf(h.w * w.w, 30.f);
    float A0 = fast_exp2(t0) + 1.f;
    float A1 = fast_exp2(t1) + 1.f;
    float A2 = fast_exp2(t2) + 1.f;
    float A3 = fast_exp2(t3) + 1.f;
    float S1 = A0 + A1, P1 = A0 * A1;
    float S2 = A2 + A3, P2 = A2 * A3;
    float num = fmaf(S1, P2, S2 * P1);
    float den = P1 * P2;
    return num * fast_rcp(den);
}

__global__ __launch_bounds__(256) void mlp_kernel(
    const float* __restrict__ x,  const float* __restrict__ b0,
    const float* __restrict__ b1, const float* __restrict__ b2,
    const float* __restrict__ ws, float* __restrict__ out) {
    // packed float4 views: index = (i>>2)*outd + o
    const float4* We0 = (const float4*)ws;             // [64][256]
    const float4* We1 = (const float4*)(ws + 65536);   // [64][256]
    const float4* We2 = (const float4*)(ws + 131072);  // [64][128]

    __shared__ __align__(16) float hA[RB][256];
    __shared__ __align__(16) float hB[RB][256];

    const int t = threadIdx.x;          // output-neuron index for layers 0,1
    const int row0 = blockIdx.x * RB;

    // stage input rows (pre-scaled by SC)
#pragma unroll
    for (int k = 0; k < RB; k++)
        hA[k][t] = x[(row0 + k) * 256 + t] * SC;
    __syncthreads();

    // ---------------- layer 0: hA -> hB (tanh) ----------------
    {
        const float bias = b0[t];
        float acc0 = 0.f, acc1 = 0.f;
#pragma unroll 4
        for (int ic = 0; ic < 64; ic++) {
            float4 w  = We0[ic * 256 + t];               // 4 K-values, one load
            float4 h0 = *(const float4*)&hA[0][ic * 4];  // LDS broadcast
            float4 h1 = *(const float4*)&hA[1][ic * 4];
            acc0 += sig4(h0, w);
            acc1 += sig4(h1, w);
        }
        hB[0][t] = (256.0f - 2.0f * acc0 + bias) * SC;
        hB[1][t] = (256.0f - 2.0f * acc1 + bias) * SC;
        __syncthreads();
    }

    // ---------------- layer 1: hB -> hA (tanh) ----------------
    {
        const float bias = b1[t];
        float acc0 = 0.f, acc1 = 0.f;
#pragma unroll 4
        for (int ic = 0; ic < 64; ic++) {
            float4 w  = We1[ic * 256 + t];
            float4 h0 = *(const float4*)&hB[0][ic * 4];
            float4 h1 = *(const float4*)&hB[1][ic * 4];
            acc0 += sig4(h0, w);
            acc1 += sig4(h1, w);
        }
        hA[0][t] = (256.0f - 2.0f * acc0 + bias) * SC;
        hA[1][t] = (256.0f - 2.0f * acc1 + bias) * SC;
        __syncthreads();
    }

    // ---------------- layer 2: hA -> out (identity matmul) ----------------
    {
        const int o = t & 127;      // output neuron
        const int r = t >> 7;       // which of the 2 rows
        float acc = 0.f;
#pragma unroll 4
        for (int ic = 0; ic < 64; ic++) {
            float4 w = We2[ic * 128 + o];
            float4 h = *(const float4*)&hA[r][ic * 4];
            acc += h.x * w.x + h.y * w.y + h.z * w.z + h.w * w.w;
        }
        out[(row0 + r) * 128 + o] = acc * INV + b2[o];  // undo SC pre-scale
    }
}

extern "C" void kernel_launch(void* const* d_in, const int* in_sizes, int n_in,
                              void* d_out, int out_size, void* d_ws, size_t ws_size,
                              hipStream_t stream) {
    const float* x  = (const float*)d_in[0];
    const float* W0 = (const float*)d_in[1];
    const float* b0 = (const float*)d_in[2];
    const int*   I0 = (const int*)  d_in[3];
    const float* W1 = (const float*)d_in[4];
    const float* b1 = (const float*)d_in[5];
    const int*   I1 = (const int*)  d_in[6];
    const float* W2 = (const float*)d_in[7];
    const float* b2 = (const float*)d_in[8];
    const int*   I2 = (const int*)  d_in[9];
    float* ws  = (float*)d_ws;    // 163840 floats = 655360 B
    float* out = (float*)d_out;

    weff_kernel<<<640, 256, 0, stream>>>(W0, I0, W1, I1, W2, I2, ws);
    mlp_kernel<<<2048 / RB, 256, 0, stream>>>(x, b0, b1, b2, ws, out);
}

// Round 5
// 114.558 us; speedup vs baseline: 1.1806x; 1.0988x over previous
//
#include <hip/hip_runtime.h>
#include <math.h>

// TeacherMLP fused forward.
// R5 changes vs R4 (model: single VALU issue port; trans ops occupy it ~12cyc,
// full-rate 2cyc -> R4 = 120cyc trans + ~96 full/mem + 29% idle per 8 sigma):
//  1) Row-packed dual-FP32: activations in LDS as v2f (row0,row1); the whole
//     sigma-tree / muls / accs become v_pk_*_f32 -> ~half the full-rate slots.
//  2) Merge-8: one rcp per 8 sigma-terms. Overflow guarded by clamping stored
//     activations at +-32 (|We|<=~0.5 => sum of 8 shifted exps <= 2^64) and the
//     exact rescale B = 2^-8*A = exp2(t-8)+2^-8 (shift folds into the fma).
//  3) 512-thr blocks, split-K (2 groups x 32 chunks): 1024 blk x 8 waves =
//     8192 waves = 100% occupancy at UNCHANGED per-element instruction count.
// Predicted: mlp 63.8 -> ~37us, VALUBusy -> ~88%, Occupancy -> ~55%.

typedef float v2f __attribute__((ext_vector_type(2)));

#define SC   2.885390081777927f      /* 2*log2(e): exp2(SC*z) = e^{2z} */
#define INV  (1.0f / 2.885390081777927f)
#define INV2PI 0.15915494309189535f
#define HS_CLAMP 32.0f               /* clamp on SC-prescaled activations */
#define C8   0.00390625f             /* 2^-8 */

__device__ __forceinline__ float fast_rcp(float x)  { return __builtin_amdgcn_rcpf(x); }
__device__ __forceinline__ float fast_exp2(float x) { return __builtin_amdgcn_exp2f(x); }
__device__ __forceinline__ v2f pk2(float a, float b) { v2f r; r.x = a; r.y = b; return r; }

__global__ void weff_kernel(const float* __restrict__ W0, const int* __restrict__ I0,
                            const float* __restrict__ W1, const int* __restrict__ I1,
                            const float* __restrict__ W2, const int* __restrict__ I2,
                            float* __restrict__ ws) {
    int tid = blockIdx.x * blockDim.x + threadIdx.x;   // 0 .. 163839
    const float* W; const int* I; float* out; int outd; int e;
    if (tid < 65536)        { W = W0; I = I0; out = ws;          outd = 256; e = tid; }
    else if (tid < 131072)  { W = W1; I = I1; out = ws + 65536;  outd = 256; e = tid - 65536; }
    else if (tid < 163840)  { W = W2; I = I2; out = ws + 131072; outd = 128; e = tid - 131072; }
    else return;
    int o = e >> 8;       // out index (in-dim always 256)
    int i = e & 255;      // in index
    float w = W[e];       // coalesced (e = o*256 + i)
    int idx = I[e];
    // branchless atoms: [id, sin, tanh, square]
    float sn = __builtin_amdgcn_sinf(w * INV2PI);
    float th = 1.0f - 2.0f * fast_rcp(fast_exp2(w * SC) + 1.0f);
    float sq = w * w;
    float v = (idx == 1) ? sn : (idx == 2) ? th : (idx == 3) ? sq : w;
    // packed store: [i/4][o][i%4] -> main loop reads float4 of 4 K-values
    out[(i >> 2) * (outd * 4) + o * 4 + (i & 3)] = v;
}

// num/den of sum_{k=0..3} 1/B_k over 4 elements, both rows packed.
// B = exp2(t-8) + 2^-8 = 2^-8 * (e^{2z}+1); shift folds into the t-fma.
struct ND { v2f n, d; };
__device__ __forceinline__ ND tree4(float4 pa, float4 pb, float4 w) {
    v2f h0 = pk2(pa.x, pa.y), h1 = pk2(pa.z, pa.w);
    v2f h2 = pk2(pb.x, pb.y), h3 = pk2(pb.z, pb.w);
    v2f t0 = h0 * w.x - 8.0f, t1 = h1 * w.y - 8.0f;   // v_pk_fma
    v2f t2 = h2 * w.z - 8.0f, t3 = h3 * w.w - 8.0f;
    v2f B0 = pk2(fast_exp2(t0.x), fast_exp2(t0.y)) + C8;
    v2f B1 = pk2(fast_exp2(t1.x), fast_exp2(t1.y)) + C8;
    v2f B2 = pk2(fast_exp2(t2.x), fast_exp2(t2.y)) + C8;
    v2f B3 = pk2(fast_exp2(t3.x), fast_exp2(t3.y)) + C8;
    v2f S1 = B0 + B1, P1 = B0 * B1;
    v2f S2 = B2 + B3, P2 = B2 * B3;
    ND r; r.n = S1 * P2 + S2 * P1; r.d = P1 * P2; return r;
}

// merge two 4-trees: sum of 8 reciprocal terms with ONE rcp per row.
__device__ __forceinline__ v2f sig8(ND a, ND b) {
    v2f num = a.n * b.d + b.n * a.d;
    v2f den = a.d * b.d;
    v2f rd  = pk2(fast_rcp(den.x), fast_rcp(den.y));
    return num * rd;
}

__global__ __launch_bounds__(512, 8) void mlp_kernel(
    const float* __restrict__ x,  const float* __restrict__ b0,
    const float* __restrict__ b1, const float* __restrict__ b2,
    const float* __restrict__ ws, float* __restrict__ out) {
    const float4* We0 = (const float4*)ws;             // [64][256] packed [ic][o][4]
    const float4* We1 = (const float4*)(ws + 65536);   // [64][256]
    const float4* We2 = (const float4*)(ws + 131072);  // [64][128]

    __shared__ __align__(16) v2f hA[256];       // [i] = (row0_i, row1_i), SC-prescaled
    __shared__ __align__(16) v2f hB[256];
    __shared__ __align__(16) v2f part[512];     // split-K partials: [2][256] or [4][128]

    const int t = threadIdx.x;     // 0..511
    const int g = t >> 8;          // K-group (wave-uniform: waves 0-3 vs 4-7)
    const int o = t & 255;         // neuron
    const int row0 = blockIdx.x * 2;

    // stage 2 input rows, prescale + clamp (clamp is a no-op for real data)
    {
        float xv = x[(row0 + g) * 256 + o] * SC;
        xv = fminf(fmaxf(xv, -HS_CLAMP), HS_CLAMP);
        ((float*)(hA + o))[g] = xv;
    }
    __syncthreads();

    // ---------------- layer 0: hA -> hB ----------------
    {
        v2f acc = pk2(0.f, 0.f);
#pragma unroll 2
        for (int icc = 0; icc < 32; icc += 2) {
            int ic = g * 32 + icc;
            float4 w0 = We0[ic * 256 + o];
            float4 w1 = We0[(ic + 1) * 256 + o];
            const float4* hp = (const float4*)(hA + ic * 4);  // uniform addr -> broadcast
            ND r0 = tree4(hp[0], hp[1], w0);
            ND r1 = tree4(hp[2], hp[3], w1);
            acc += sig8(r0, r1);
        }
        part[g * 256 + o] = acc;
        __syncthreads();
        // combine: this thread produces h for (row g, neuron o)
        float s = ((const float*)(part + o))[g] + ((const float*)(part + 256 + o))[g];
        float h = (256.0f - 0.0078125f * s + b0[o]) * SC;   // 2^-7 undoes B-scale x2
        h = fminf(fmaxf(h, -HS_CLAMP), HS_CLAMP);
        ((float*)(hB + o))[g] = h;
        __syncthreads();
    }

    // ---------------- layer 1: hB -> hA ----------------
    {
        v2f acc = pk2(0.f, 0.f);
#pragma unroll 2
        for (int icc = 0; icc < 32; icc += 2) {
            int ic = g * 32 + icc;
            float4 w0 = We1[ic * 256 + o];
            float4 w1 = We1[(ic + 1) * 256 + o];
            const float4* hp = (const float4*)(hB + ic * 4);
            ND r0 = tree4(hp[0], hp[1], w0);
            ND r1 = tree4(hp[2], hp[3], w1);
            acc += sig8(r0, r1);
        }
        part[g * 256 + o] = acc;
        __syncthreads();
        float s = ((const float*)(part + o))[g] + ((const float*)(part + 256 + o))[g];
        float h = (256.0f - 0.0078125f * s + b1[o]) * SC;
        h = fminf(fmaxf(h, -HS_CLAMP), HS_CLAMP);
        ((float*)(hA + o))[g] = h;
        __syncthreads();
    }

    // ---------------- layer 2: hA -> out (identity matmul, 4-way split-K) --
    {
        const int o2 = t & 127;
        const int q  = t >> 7;     // K-quarter
        v2f acc = pk2(0.f, 0.f);
#pragma unroll 4
        for (int icc = 0; icc < 16; icc++) {
            int ic = q * 16 + icc;
            float4 w = We2[ic * 128 + o2];
            const float4* hp = (const float4*)(hA + ic * 4);
            float4 pa = hp[0], pb = hp[1];
            v2f h0 = pk2(pa.x, pa.y), h1 = pk2(pa.z, pa.w);
            v2f h2 = pk2(pb.x, pb.y), h3 = pk2(pb.z, pb.w);
            acc += h0 * w.x + h1 * w.y;   // v_pk_fma chain
            acc += h2 * w.z + h3 * w.w;
        }
        part[q * 128 + o2] = acc;
        __syncthreads();
        if (t < 256) {
            int r = t >> 7, oo = t & 127;
            float s = ((const float*)(part + oo))[r]
                    + ((const float*)(part + 128 + oo))[r]
                    + ((const float*)(part + 256 + oo))[r]
                    + ((const float*)(part + 384 + oo))[r];
            out[(row0 + r) * 128 + oo] = s * INV + b2[oo];  // undo SC prescale
        }
    }
}

extern "C" void kernel_launch(void* const* d_in, const int* in_sizes, int n_in,
                              void* d_out, int out_size, void* d_ws, size_t ws_size,
                              hipStream_t stream) {
    const float* x  = (const float*)d_in[0];
    const float* W0 = (const float*)d_in[1];
    const float* b0 = (const float*)d_in[2];
    const int*   I0 = (const int*)  d_in[3];
    const float* W1 = (const float*)d_in[4];
    const float* b1 = (const float*)d_in[5];
    const int*   I1 = (const int*)  d_in[6];
    const float* W2 = (const float*)d_in[7];
    const float* b2 = (const float*)d_in[8];
    const int*   I2 = (const int*)  d_in[9];
    float* ws  = (float*)d_ws;    // 163840 floats = 655360 B
    float* out = (float*)d_out;

    weff_kernel<<<640, 256, 0, stream>>>(W0, I0, W1, I1, W2, I2, ws);
    mlp_kernel<<<1024, 512, 0, stream>>>(x, b0, b1, b2, ws, out);
}